// Round 1
// baseline (239.129 us; speedup 1.0000x reference)
//
#include <hip/hip_runtime.h>
#include <hip/hip_bf16.h>

typedef unsigned short u16;
typedef __bf16 bf16x8 __attribute__((ext_vector_type(8)));
typedef float f32x4 __attribute__((ext_vector_type(4)));
typedef unsigned short u16x8 __attribute__((ext_vector_type(8)));

// round-to-nearest-even fp32 -> bf16
__device__ inline u16 f2bf(float f) {
    union { float f; unsigned u; } v; v.f = f;
    unsigned r = v.u + 0x7fffu + ((v.u >> 16) & 1u);
    return (u16)(r >> 16);
}

// ---------------------------------------------------------------------------
// Convert x and 4 weights to bf16, contiguous in ws:
//   [x_bf 4194304][wq 1048576][wk][wv][wo]
// ---------------------------------------------------------------------------
__global__ void convert_kernel(const float* __restrict__ x,
                               const float* __restrict__ wq, const float* __restrict__ wk,
                               const float* __restrict__ wv, const float* __restrict__ wo,
                               u16* __restrict__ dst) {
    long g = (long)blockIdx.x * blockDim.x + threadIdx.x;  // group of 4 elements
    const float* src; long base;
    const long GX = 1048576, GW = 262144;  // groups: x = 4.19M els, each w = 1.05M els
    if (g < GX)            { src = x;  base = 0; }
    else if (g < GX + GW)  { src = wq; base = GX; }
    else if (g < GX + 2*GW){ src = wk; base = GX + GW; }
    else if (g < GX + 3*GW){ src = wv; base = GX + 2*GW; }
    else                   { src = wo; base = GX + 3*GW; }
    long rel = g - base;
    float4 v = reinterpret_cast<const float4*>(src)[rel];
    ushort4 o;
    o.x = f2bf(v.x); o.y = f2bf(v.y); o.z = f2bf(v.z); o.w = f2bf(v.w);
    reinterpret_cast<ushort4*>(dst)[g] = o;
}

// ---------------------------------------------------------------------------
// Shared GEMM mainloop: C[128x128] tile of A[T][1024] * W[N][1024]^T.
// 256 threads = 4 waves (2x2), each wave 64x64 via 4x4 frags of 16x16x32 bf16.
// LDS rows padded to 72 els (144 B, 16B-aligned, conflict-free-ish).
// ---------------------------------------------------------------------------
#define LDP 72

__device__ inline void gemm_mainloop(const u16* __restrict__ A, const u16* __restrict__ W,
                                     int t0, int n0, u16* As, u16* Bs, f32x4 acc[4][4]) {
    const int tid = threadIdx.x;
    const int wid = tid >> 6, lane = tid & 63, quad = lane >> 4, ln = lane & 15;
    const int wm = wid >> 1, wn = wid & 1;
#pragma unroll
    for (int im = 0; im < 4; im++)
#pragma unroll
        for (int in = 0; in < 4; in++) acc[im][in] = (f32x4){0.f, 0.f, 0.f, 0.f};

    for (int k0 = 0; k0 < 1024; k0 += 64) {
#pragma unroll
        for (int i = 0; i < 4; i++) {
            int c = i * 256 + tid;       // 1024 chunks of 8 bf16
            int row = c >> 3, kc = c & 7;
            u16x8 av = *reinterpret_cast<const u16x8*>(A + (long)(t0 + row) * 1024 + k0 + kc * 8);
            u16x8 bv = *reinterpret_cast<const u16x8*>(W + (long)(n0 + row) * 1024 + k0 + kc * 8);
            *reinterpret_cast<u16x8*>(As + row * LDP + kc * 8) = av;
            *reinterpret_cast<u16x8*>(Bs + row * LDP + kc * 8) = bv;
        }
        __syncthreads();
#pragma unroll
        for (int ks = 0; ks < 2; ks++) {
            bf16x8 af[4], bf[4];
#pragma unroll
            for (int im = 0; im < 4; im++)
                af[im] = *reinterpret_cast<const bf16x8*>(As + (wm * 64 + im * 16 + ln) * LDP + ks * 32 + quad * 8);
#pragma unroll
            for (int in = 0; in < 4; in++)
                bf[in] = *reinterpret_cast<const bf16x8*>(Bs + (wn * 64 + in * 16 + ln) * LDP + ks * 32 + quad * 8);
#pragma unroll
            for (int im = 0; im < 4; im++)
#pragma unroll
                for (int in = 0; in < 4; in++)
                    acc[im][in] = __builtin_amdgcn_mfma_f32_16x16x32_bf16(af[im], bf[in], acc[im][in], 0, 0, 0);
        }
        __syncthreads();
    }
}

// ---------------------------------------------------------------------------
// QKV projection. z = 0:q, 1:k, 2:v.
//   q_ws/k_ws: [bh][s][64] bf16 (q pre-scaled by 1/8 for the softmax scale)
//   v_ws:      [bh][64][s] bf16 (transposed so attention PV B-frags are contiguous)
// ---------------------------------------------------------------------------
__global__ void qkv_gemm(const u16* __restrict__ x_bf,
                         const u16* __restrict__ wq, const u16* __restrict__ wk, const u16* __restrict__ wv,
                         const float* __restrict__ sq, const float* __restrict__ sk, const float* __restrict__ sv,
                         const float* __restrict__ bq, const float* __restrict__ bk, const float* __restrict__ bv,
                         u16* __restrict__ q_ws, u16* __restrict__ k_ws, u16* __restrict__ v_ws) {
    __shared__ u16 As[128 * LDP];
    __shared__ u16 Bs[128 * LDP];
    const int z = blockIdx.z;
    const u16* W   = (z == 0) ? wq : (z == 1) ? wk : wv;
    const float* sp = (z == 0) ? sq : (z == 1) ? sk : sv;
    const float* bp = (z == 0) ? bq : (z == 1) ? bk : bv;
    u16* dst = (z == 0) ? q_ws : (z == 1) ? k_ws : v_ws;
    const float extra = (z == 0) ? 0.125f : 1.0f;   // fold 1/sqrt(64) into q
    const int t0 = blockIdx.x * 128, n0 = blockIdx.y * 128;

    f32x4 acc[4][4];
    gemm_mainloop(x_bf, W, t0, n0, As, Bs, acc);

    const int tid = threadIdx.x;
    const int wid = tid >> 6, lane = tid & 63, quad = lane >> 4, ln = lane & 15;
    const int wm = wid >> 1, wn = wid & 1;
    const float s = sp[0] * extra;
#pragma unroll
    for (int in = 0; in < 4; in++) {
        int col = n0 + wn * 64 + in * 16 + ln;
        float bias = bp[col] * extra;
        int h = col >> 6, d = col & 63;
#pragma unroll
        for (int im = 0; im < 4; im++) {
            int rbase = t0 + wm * 64 + im * 16 + quad * 4;
#pragma unroll
            for (int j = 0; j < 4; j++) {
                int t = rbase + j;
                int b = t >> 11, ss = t & 2047;
                int bh = b * 16 + h;
                float val = acc[im][in][j] * s + bias;
                long idx = (z < 2) ? ((long)(bh * 2048 + ss) * 64 + d)
                                   : ((long)(bh * 64 + d) * 2048 + ss);
                dst[idx] = f2bf(val);
            }
        }
    }
}

// ---------------------------------------------------------------------------
// Attention: per (q-tile of 128, bh). No-max softmax (scores bounded):
// accumulate exp(s)@V unnormalized; denominator via ones-row appended to V^T.
// ---------------------------------------------------------------------------
__global__ void attn_kernel(const u16* __restrict__ q_ws, const u16* __restrict__ k_ws,
                            const u16* __restrict__ v_ws, u16* __restrict__ ctx) {
    __shared__ u16 Kt[64 * LDP];    // [key][d]
    __shared__ u16 Vt[80 * LDP];    // [d'][key]; d'=64 row = ones, 65..79 = zeros
    __shared__ u16 Pt[128 * LDP];   // [q][key] exp(scores) in bf16

    const int tid = threadIdx.x;
    const int wid = tid >> 6, lane = tid & 63, quad = lane >> 4, ln = lane & 15;
    const int bh = blockIdx.y;
    const int q0 = blockIdx.x * 128;
    const u16* qbase = q_ws + (long)bh * 2048 * 64;
    const u16* kbase = k_ws + (long)bh * 2048 * 64;
    const u16* vbase = v_ws + (long)bh * 64 * 2048;

    // ones/zeros tail of Vt (rows 64..79), written once
    for (int i = tid; i < 16 * LDP; i += 256) {
        int r = i / LDP, c = i % LDP;
        Vt[(64 + r) * LDP + c] = (r == 0 && c < 64) ? (u16)0x3F80 : (u16)0;
    }

    // Q fragments held in registers for the whole K loop (q pre-scaled by 1/8)
    bf16x8 aq[2][2];
#pragma unroll
    for (int qt = 0; qt < 2; qt++)
#pragma unroll
        for (int ks = 0; ks < 2; ks++)
            aq[qt][ks] = *reinterpret_cast<const bf16x8*>(
                qbase + (long)(q0 + wid * 32 + qt * 16 + ln) * 64 + ks * 32 + quad * 8);

    f32x4 acc_o[2][4];
    f32x4 acc_l[2];
#pragma unroll
    for (int qt = 0; qt < 2; qt++) {
        acc_l[qt] = (f32x4){0.f, 0.f, 0.f, 0.f};
#pragma unroll
        for (int dt = 0; dt < 4; dt++) acc_o[qt][dt] = (f32x4){0.f, 0.f, 0.f, 0.f};
    }

    for (int kt = 0; kt < 2048; kt += 64) {
        // stage K [64 keys][64 d] and V^T [64 d][64 keys]
#pragma unroll
        for (int i = 0; i < 2; i++) {
            int c = i * 256 + tid;
            int row = c >> 3, kc = c & 7;
            u16x8 kv = *reinterpret_cast<const u16x8*>(kbase + (long)(kt + row) * 64 + kc * 8);
            *reinterpret_cast<u16x8*>(Kt + row * LDP + kc * 8) = kv;
            u16x8 vv = *reinterpret_cast<const u16x8*>(vbase + (long)row * 2048 + kt + kc * 8);
            *reinterpret_cast<u16x8*>(Vt + row * LDP + kc * 8) = vv;
        }
        __syncthreads();

        // S = Q K^T  (already includes 1/sqrt(64) via q pre-scale)
        f32x4 sfr[2][4];
#pragma unroll
        for (int k8 = 0; k8 < 4; k8++) {
            bf16x8 b0 = *reinterpret_cast<const bf16x8*>(Kt + (k8 * 16 + ln) * LDP + quad * 8);
            bf16x8 b1 = *reinterpret_cast<const bf16x8*>(Kt + (k8 * 16 + ln) * LDP + 32 + quad * 8);
#pragma unroll
            for (int qt = 0; qt < 2; qt++) {
                f32x4 t = (f32x4){0.f, 0.f, 0.f, 0.f};
                t = __builtin_amdgcn_mfma_f32_16x16x32_bf16(aq[qt][0], b0, t, 0, 0, 0);
                t = __builtin_amdgcn_mfma_f32_16x16x32_bf16(aq[qt][1], b1, t, 0, 0, 0);
                sfr[qt][k8] = t;
            }
        }

        // P = exp(S) -> LDS (C-layout -> A-layout round trip; wave-local rows)
#pragma unroll
        for (int qt = 0; qt < 2; qt++)
#pragma unroll
            for (int k8 = 0; k8 < 4; k8++)
#pragma unroll
                for (int j = 0; j < 4; j++) {
                    float p = __expf(sfr[qt][k8][j]);
                    Pt[(wid * 32 + qt * 16 + quad * 4 + j) * LDP + k8 * 16 + ln] = f2bf(p);
                }

        // O += P V ; l += P 1  (dt==4 tile hits the ones row of Vt)
#pragma unroll
        for (int step = 0; step < 2; step++) {
            bf16x8 ap[2];
#pragma unroll
            for (int qt = 0; qt < 2; qt++)
                ap[qt] = *reinterpret_cast<const bf16x8*>(
                    Pt + (wid * 32 + qt * 16 + ln) * LDP + step * 32 + quad * 8);
#pragma unroll
            for (int dt = 0; dt < 5; dt++) {
                bf16x8 bv = *reinterpret_cast<const bf16x8*>(
                    Vt + (dt * 16 + ln) * LDP + step * 32 + quad * 8);
#pragma unroll
                for (int qt = 0; qt < 2; qt++) {
                    if (dt < 4)
                        acc_o[qt][dt] = __builtin_amdgcn_mfma_f32_16x16x32_bf16(ap[qt], bv, acc_o[qt][dt], 0, 0, 0);
                    else
                        acc_l[qt] = __builtin_amdgcn_mfma_f32_16x16x32_bf16(ap[qt], bv, acc_l[qt], 0, 0, 0);
                }
            }
        }
        __syncthreads();
    }

    // normalize and write ctx [t][h*64+d] bf16
    const int b = bh >> 4, h = bh & 15;
#pragma unroll
    for (int qt = 0; qt < 2; qt++) {
#pragma unroll
        for (int j = 0; j < 4; j++) {
            float l = __shfl(acc_l[qt][j], lane & 48, 64);  // broadcast col 0 of quad group
            float rinv = 1.0f / l;
            int t = b * 2048 + q0 + wid * 32 + qt * 16 + quad * 4 + j;
#pragma unroll
            for (int dt = 0; dt < 4; dt++) {
                float val = acc_o[qt][dt][j] * rinv;
                ctx[(long)t * 1024 + h * 64 + dt * 16 + ln] = f2bf(val);
            }
        }
    }
}

// ---------------------------------------------------------------------------
// Output projection: d_out[t][o] = ctx @ wo^T * s_o + b_o  (fp32 out)
// ---------------------------------------------------------------------------
__global__ void o_gemm(const u16* __restrict__ ctx, const u16* __restrict__ wo,
                       const float* __restrict__ so, const float* __restrict__ bo,
                       float* __restrict__ out) {
    __shared__ u16 As[128 * LDP];
    __shared__ u16 Bs[128 * LDP];
    const int t0 = blockIdx.x * 128, n0 = blockIdx.y * 128;
    f32x4 acc[4][4];
    gemm_mainloop(ctx, wo, t0, n0, As, Bs, acc);

    const int tid = threadIdx.x;
    const int wid = tid >> 6, lane = tid & 63, quad = lane >> 4, ln = lane & 15;
    const int wm = wid >> 1, wn = wid & 1;
    const float s = so[0];
#pragma unroll
    for (int in = 0; in < 4; in++) {
        int col = n0 + wn * 64 + in * 16 + ln;
        float bias = bo[col];
#pragma unroll
        for (int im = 0; im < 4; im++) {
            int rbase = t0 + wm * 64 + im * 16 + quad * 4;
#pragma unroll
            for (int j = 0; j < 4; j++)
                out[(long)(rbase + j) * 1024 + col] = acc[im][in][j] * s + bias;
        }
    }
}

// ---------------------------------------------------------------------------
extern "C" void kernel_launch(void* const* d_in, const int* in_sizes, int n_in,
                              void* d_out, int out_size, void* d_ws, size_t ws_size,
                              hipStream_t stream) {
    const float* x   = (const float*)d_in[0];
    const float* w_q = (const float*)d_in[1];
    const float* s_q = (const float*)d_in[2];
    const float* b_q = (const float*)d_in[3];
    const float* w_k = (const float*)d_in[4];
    const float* s_k = (const float*)d_in[5];
    const float* b_k = (const float*)d_in[6];
    const float* w_v = (const float*)d_in[7];
    const float* s_v = (const float*)d_in[8];
    const float* b_v = (const float*)d_in[9];
    const float* w_o = (const float*)d_in[10];
    const float* s_o = (const float*)d_in[11];
    const float* b_o = (const float*)d_in[12];

    if (ws_size < (size_t)50331648) return;  // need 48 MB of scratch

    u16* ws     = (u16*)d_ws;
    u16* x_bf   = ws;                    // 4096*1024
    u16* wq_bf  = x_bf  + 4194304;       // 1024*1024 each
    u16* wk_bf  = wq_bf + 1048576;
    u16* wv_bf  = wk_bf + 1048576;
    u16* wo_bf  = wv_bf + 1048576;
    u16* q_ws   = wo_bf + 1048576;       // [32 bh][2048 s][64 d]
    u16* k_ws   = q_ws  + 4194304;
    u16* v_ws   = k_ws  + 4194304;       // [32 bh][64 d][2048 s]
    u16* ctx_ws = v_ws  + 4194304;       // [4096 t][1024]

    convert_kernel<<<dim3(8192), dim3(256), 0, stream>>>(x, w_q, w_k, w_v, w_o, ws);
    qkv_gemm<<<dim3(32, 8, 3), dim3(256), 0, stream>>>(x_bf, wq_bf, wk_bf, wv_bf,
                                                       s_q, s_k, s_v, b_q, b_k, b_v,
                                                       q_ws, k_ws, v_ws);
    attn_kernel<<<dim3(16, 32), dim3(256), 0, stream>>>(q_ws, k_ws, v_ws, ctx_ws);
    o_gemm<<<dim3(32, 8), dim3(256), 0, stream>>>(ctx_ws, wo_bf, s_o, b_o, (float*)d_out);
}